// Round 6
// baseline (71.932 us; speedup 1.0000x reference)
//
#include <hip/hip_runtime.h>

typedef float v2f __attribute__((ext_vector_type(2)));
typedef float v4f __attribute__((ext_vector_type(4)));

#define EPS 1e-7f

// mantissa_map: (|v|+eps) -> mantissa m in [1,2); result = m>=1.5 ? m/2 : m  -> [0.75,1.5)
__device__ __forceinline__ float mant_map(float v) {
    float a = fabsf(v) + EPS;
    unsigned int bi = __float_as_uint(a);
    float m = __uint_as_float((bi & 0x007FFFFFu) | 0x3F800000u);
    return (m >= 1.5f) ? 0.5f * m : m;
}

// Block = (16,4) = 64 threads = 1 wave. One block: 28-row x 56-col slab of one
// (b,c) plane. Thread (lx,ty): output cols 4lx..4lx+3, rows ty*7..ty*7+6.
// out = sum_taps u*B + v*C  with u=x, v=x/M1, B=w/M2, C=B*(M2-1).
__global__ __launch_bounds__(64, 2) void wconv_kernel(const float* __restrict__ x,
                                                      const float* __restrict__ w,
                                                      float* __restrict__ out) {
    __shared__ v2f sp[34][64];    // rows y0-3..y0+30, cols -3..60 (17.4 KB)
    __shared__ float swt[7][16];  // [i][2j]=B, [2j+1]=C (j=0..6), cols 14..15 pad

    const int lx = threadIdx.x;   // 0..15 (col quad; active if <14)
    const int ty = threadIdx.y;   // 0..3
    const int tid = ty * 16 + lx;
    const int c = blockIdx.x;
    const int b = blockIdx.y;
    const int tz = blockIdx.z;    // 0..1 (28-row slab)

    const int y0 = 28 * tz;
    const int g0 = (tz == 0) ? 0 : 25;    // first real input row staged
    const int l0 = (tz == 0) ? 3 : 0;     // its LDS row
    const int z0 = (tz == 0) ? 0 : 31;    // first of 3 fully-zero LDS rows

    const long plane = (long)(b * 192 + c) * 3136;
    const float* xp = x + plane;

    // --- fused weight prep: packed (B,C) pairs, row-padded to 64 B ---
    if (tid < 49) {
        float wv = w[c * 49 + tid];
        float M2 = mant_map(wv);
        float B = wv / M2;
        int i = tid / 7, j = tid - 7 * i;
        swt[i][2 * j] = B;
        swt[i][2 * j + 1] = B * (M2 - 1.0f);
    } else if (tid < 56) {
        int i = tid - 49;
        swt[i][14] = 0.0f;
        swt[i][15] = 0.0f;
    }

    // --- halo zero: 3 full rows + side cols of the 31 real rows ---
    for (int t = tid; t < 192; t += 64)
        ((v2f*)sp)[z0 * 64 + t] = (v2f){0.f, 0.f};
    for (int t = tid; t < 248; t += 64) {
        int r = l0 + (t >> 3), k = t & 7;
        int col = (k < 3) ? k : 56 + k;   // cols 0,1,2, 59..63
        sp[r][col] = (v2f){0.f, 0.f};
    }

    // --- interior staging: 31 rows x 14 dword4-quads, branch-free ---
    for (int t = tid; t < 434; t += 64) {
        int r = t / 14, q4 = t % 14;
        v4f u4 = *(const v4f*)(xp + (g0 + r) * 56 + q4 * 4);
        v2f* dst = &sp[l0 + r][3 + q4 * 4];
        dst[0] = (v2f){u4.x, u4.x * __builtin_amdgcn_rcpf(mant_map(u4.x))};
        dst[1] = (v2f){u4.y, u4.y * __builtin_amdgcn_rcpf(mant_map(u4.y))};
        dst[2] = (v2f){u4.z, u4.z * __builtin_amdgcn_rcpf(mant_map(u4.z))};
        dst[3] = (v2f){u4.w, u4.w * __builtin_amdgcn_rcpf(mant_map(u4.w))};
    }
    __syncthreads();

    if (lx < 14) {
        const int x0 = lx * 4;    // output col base (x4 -> 32B-aligned LDS reads)
        const int rb = ty * 7;    // output row base within slab

        v2f acc[4][7];
        #pragma unroll
        for (int c4 = 0; c4 < 4; ++c4)
            #pragma unroll
            for (int r = 0; r < 7; ++r) acc[c4][r] = (v2f){0.f, 0.f};

        #pragma unroll
        for (int ir = 0; ir < 13; ++ir) {
            // 10 pixels (u,v) covering all 4 columns' 7-tap windows: 5x b128
            const v4f* q = (const v4f*)&sp[rb + ir][x0];
            v4f q0 = q[0], q1 = q[1], q2 = q[2], q3 = q[3], q4 = q[4];
            v2f p[10] = {{q0.x, q0.y}, {q0.z, q0.w}, {q1.x, q1.y}, {q1.z, q1.w},
                         {q2.x, q2.y}, {q2.z, q2.w}, {q3.x, q3.y}, {q3.z, q3.w},
                         {q4.x, q4.y}, {q4.z, q4.w}};
            #pragma unroll
            for (int ry = 0; ry < 7; ++ry) {
                const int i = ir - ry;          // weight row; compile-time resolved
                if (i >= 0 && i <= 6) {
                    // 4 broadcast b128 reads serve all 4 columns x 7 taps
                    const v4f* wr = (const v4f*)swt[i];
                    v4f w0 = wr[0], w1 = wr[1], w2 = wr[2], w3 = wr[3];
                    v2f wt2[7] = {{w0.x, w0.y}, {w0.z, w0.w}, {w1.x, w1.y},
                                  {w1.z, w1.w}, {w2.x, w2.y}, {w2.z, w2.w},
                                  {w3.x, w3.y}};
                    #pragma unroll
                    for (int c4 = 0; c4 < 4; ++c4)
                        #pragma unroll
                        for (int j = 0; j < 7; ++j)
                            acc[c4][ry] += p[c4 + j] * wt2[j];   // v_pk_fma_f32
                }
            }
        }

        #pragma unroll
        for (int ry = 0; ry < 7; ++ry) {
            v4f o = {acc[0][ry].x + acc[0][ry].y, acc[1][ry].x + acc[1][ry].y,
                     acc[2][ry].x + acc[2][ry].y, acc[3][ry].x + acc[3][ry].y};
            *(v4f*)&out[plane + (y0 + rb + ry) * 56 + x0] = o;   // 16B store
        }
    }
}

extern "C" void kernel_launch(void* const* d_in, const int* in_sizes, int n_in,
                              void* d_out, int out_size, void* d_ws, size_t ws_size,
                              hipStream_t stream) {
    const float* x = (const float*)d_in[0];   // (4,192,56,56) fp32
    const float* w = (const float*)d_in[1];   // (192,1,7,7) fp32
    float* out = (float*)d_out;

    hipLaunchKernelGGL(wconv_kernel, dim3(192, 4, 2), dim3(16, 4), 0, stream, x, w, out);
}